// Round 13
// baseline (407.356 us; speedup 1.0000x reference)
//
#include <hip/hip_runtime.h>
#include <math.h>

#define LNODES 2048
#define NEDGE 16384
#define GBIG 32
#define GSM 4
#define NCOUT 256
#define BN_EPS 1e-5f
#define ND 32  // dst nodes per agg block

typedef unsigned short u16;
typedef __attribute__((ext_vector_type(8))) short bf16x8;
typedef __attribute__((ext_vector_type(4))) float f32x4;
typedef __attribute__((ext_vector_type(4))) unsigned u32x4;
typedef __attribute__((ext_vector_type(2))) unsigned u32x2;

__device__ __forceinline__ unsigned pk2(float a, float b) {  // a->lo, b->hi
  unsigned ua = __float_as_uint(a); ua += 0x7fffu + ((ua >> 16) & 1u);
  unsigned ub = __float_as_uint(b); ub += 0x7fffu + ((ub >> 16) & 1u);
  return (ua >> 16) | (ub & 0xffff0000u);
}
__device__ __forceinline__ float blo(unsigned u) { return __uint_as_float(u << 16); }
__device__ __forceinline__ float bhi(unsigned u) { return __uint_as_float(u & 0xffff0000u); }

__device__ __forceinline__ void nt_store4(void* p, unsigned a, unsigned b,
                                          unsigned c, unsigned d) {
  u32x4 v = {a, b, c, d};
  __builtin_nontemporal_store(v, reinterpret_cast<u32x4*>(p));
}
__device__ __forceinline__ void nt_store2(void* p, unsigned a, unsigned b) {
  u32x2 v = {a, b};
  __builtin_nontemporal_store(v, reinterpret_cast<u32x2*>(p));
}
__device__ __forceinline__ void nt_storef4(void* p, float a, float b, float c, float d) {
  f32x4 v = {a, b, c, d};
  __builtin_nontemporal_store(v, reinterpret_cast<f32x4*>(p));
}

// ---------------- setup: degree, dis, CSR ----------------

__global__ __launch_bounds__(256) void count_deg_k(const int* __restrict__ ei,
                                                   float* __restrict__ deg,
                                                   int* __restrict__ cnt) {
  int e = blockIdx.x * 256 + threadIdx.x;
  if (e < NEDGE) {
    int d = ei[NEDGE + e];
    atomicAdd(&deg[d], 1.0f);
    atomicAdd(&cnt[d], 1);
  }
}

__global__ __launch_bounds__(256) void dis_k(const float* __restrict__ deg,
                                             float* __restrict__ dis,
                                             float* __restrict__ selfn) {
  int i = blockIdx.x * 256 + threadIdx.x;
  if (i < LNODES) {
    float di = rsqrtf(deg[i] + 2.0f);  // improved=True self loop weight 2
    dis[i] = di;
    selfn[i] = 2.0f * di * di;
  }
}

__global__ __launch_bounds__(256) void scan_k(const int* __restrict__ cnt,
                                              int* __restrict__ rp) {
  __shared__ int part[256];
  int t = threadIdx.x;
  int base = t * 8;
  int loc[8];
  int s = 0;
#pragma unroll
  for (int j = 0; j < 8; ++j) { loc[j] = s; s += cnt[base + j]; }
  part[t] = s;
  __syncthreads();
  for (int off = 1; off < 256; off <<= 1) {
    int v = (t >= off) ? part[t - off] : 0;
    __syncthreads();
    part[t] += v;
    __syncthreads();
  }
  int excl = (t == 0) ? 0 : part[t - 1];
#pragma unroll
  for (int j = 0; j < 8; ++j) rp[base + j] = excl + loc[j];
  if (t == 255) rp[LNODES] = part[255];
}

__global__ __launch_bounds__(256) void fill_k(const int* __restrict__ ei,
                                              const int* __restrict__ rp,
                                              int* __restrict__ fillc,
                                              const float* __restrict__ dis,
                                              int* __restrict__ col,
                                              float* __restrict__ wn) {
  int e = blockIdx.x * 256 + threadIdx.x;
  if (e < NEDGE) {
    int s = ei[e], d = ei[NEDGE + e];
    int pos = rp[d] + atomicAdd(&fillc[d], 1);
    col[pos] = s;
    wn[pos] = dis[s] * dis[d];
  }
}

// ---------------- x [G][Cin][L] f32 -> XT [G][L][Cin] bf16 ----------------
__global__ __launch_bounds__(256) void trans_k(const float* __restrict__ X,
                                               u16* __restrict__ XT, int Cin) {
  __shared__ float T[64][65];  // [ci_local][node_local]
  const int g = blockIdx.z;
  const int n0 = blockIdx.x * 64;
  const int c0 = blockIdx.y * 64;
  const int tr = threadIdx.x >> 4;
  const int tc = (threadIdx.x & 15) * 4;
#pragma unroll
  for (int p = 0; p < 4; ++p) {
    int ci = c0 + tr + p * 16;
    float4 v = *reinterpret_cast<const float4*>(&X[((size_t)g * Cin + ci) * LNODES + n0 + tc]);
    T[tr + p * 16][tc + 0] = v.x; T[tr + p * 16][tc + 1] = v.y;
    T[tr + p * 16][tc + 2] = v.z; T[tr + p * 16][tc + 3] = v.w;
  }
  __syncthreads();
#pragma unroll
  for (int p = 0; p < 4; ++p) {
    int nd = tr + p * 16;
    uint2 o = {pk2(T[tc + 0][nd], T[tc + 1][nd]), pk2(T[tc + 2][nd], T[tc + 3][nd])};
    *reinterpret_cast<uint2*>(&XT[((size_t)g * LNODES + n0 + nd) * Cin + c0 + tc]) = o;
  }
}

// ---------------- all 6 weights: W [Ci][256] f32 -> WT [256][Ci] bf16, one launch ----------------
struct WCvt {
  const float* src[6];
  u16* dst[6];
  int ci[6];
};
__global__ __launch_bounds__(256) void cvtw_all_k(WCvt wp) {
  __shared__ float T[64][65];
  const int w = blockIdx.z;
  const int Ci = wp.ci[w];
  const int ci0 = blockIdx.y * 64;
  if (ci0 >= Ci) return;
  const float* W = wp.src[w];
  u16* WT = wp.dst[w];
  const int co0 = blockIdx.x * 64;
  const int tr = threadIdx.x >> 4;
  const int tc = (threadIdx.x & 15) * 4;
#pragma unroll
  for (int p = 0; p < 4; ++p) {
    int ci = ci0 + tr + p * 16;
    float4 v = *reinterpret_cast<const float4*>(&W[(size_t)ci * NCOUT + co0 + tc]);
    T[tr + p * 16][tc + 0] = v.x; T[tr + p * 16][tc + 1] = v.y;
    T[tr + p * 16][tc + 2] = v.z; T[tr + p * 16][tc + 3] = v.w;
  }
  __syncthreads();
#pragma unroll
  for (int p = 0; p < 4; ++p) {
    int co = tr + p * 16;
    uint2 o = {pk2(T[tc + 0][co], T[tc + 1][co]), pk2(T[tc + 2][co], T[tc + 3][co])};
    *reinterpret_cast<uint2*>(&WT[(size_t)(co0 + co) * Ci + ci0 + tc]) = o;
  }
}

// ---------------- layer-0 max-pool over N=8 (raw bf16 input) ----------------
__global__ __launch_bounds__(256) void pool_bf_k(const u16* __restrict__ X,
                                                 u16* __restrict__ XP, int per) {
  int i = blockIdx.x * 256 + threadIdx.x;
  size_t f = (size_t)i * 8;
  int b = (int)(f / per);
  size_t rem = f - (size_t)b * per;
  const u16* base = X + (size_t)b * 8 * per + rem;
  uint4 u = *reinterpret_cast<const uint4*>(base);
  float m0 = blo(u.x), m1 = bhi(u.x), m2 = blo(u.y), m3 = bhi(u.y);
  float m4 = blo(u.z), m5 = bhi(u.z), m6 = blo(u.w), m7 = bhi(u.w);
#pragma unroll
  for (int j = 1; j < 8; ++j) {
    uint4 v = *reinterpret_cast<const uint4*>(base + (size_t)j * per);
    m0 = fmaxf(m0, blo(v.x)); m1 = fmaxf(m1, bhi(v.x));
    m2 = fmaxf(m2, blo(v.y)); m3 = fmaxf(m3, bhi(v.y));
    m4 = fmaxf(m4, blo(v.z)); m5 = fmaxf(m5, bhi(v.z));
    m6 = fmaxf(m6, blo(v.w)); m7 = fmaxf(m7, bhi(v.w));
  }
  uint4 o = {pk2(m0, m1), pk2(m2, m3), pk2(m4, m5), pk2(m6, m7)};
  *reinterpret_cast<uint4*>(XP + (size_t)b * per + rem) = o;
}

// ---------------- coef reduction helper: shards -> LDS k1/k2/cc ----------------
// st layout per layer: sum1[8][256] | sq1 | sum2 | sq2 (floats, 8192 total)
__device__ __forceinline__ void coef_ld(const float* __restrict__ st,
                                        const float* __restrict__ ga,
                                        const float* __restrict__ be,
                                        const float* __restrict__ gs,
                                        const float* __restrict__ bes,
                                        float* lk1, float* lk2, float* lcc, int t) {
  float sA = 0.f, qA = 0.f, sB = 0.f, qB = 0.f;
#pragma unroll
  for (int x = 0; x < 8; ++x) {
    sA += st[x * NCOUT + t];
    qA += st[2048 + x * NCOUT + t];
    sB += st[4096 + x * NCOUT + t];
    qB += st[6144 + x * NCOUT + t];
  }
  const float c1 = (float)(GBIG * LNODES), c2 = (float)(GSM * LNODES);
  float mA = sA / c1;
  float vA = qA / c1 - mA * mA;
  float kA = ga[t] * rsqrtf(vA + BN_EPS);
  float mB = sB / c2;
  float vB = qB / c2 - mB * mB;
  float kB = gs[t] * rsqrtf(vB + BN_EPS);
  lk1[t] = kA;
  lk2[t] = kB;
  lcc[t] = be[t] - kA * mA + bes[t] - kB * mB;
}

// ---------------- bf16 MFMA GEMM, combined sym+big, fused BN(+pool) staging ----------------
template <int MODE>
__global__ __launch_bounds__(256) void gemm_all_k(const u16* __restrict__ Xbig,
                                                  const u16* __restrict__ xp,
                                                  const u16* __restrict__ AGG1,
                                                  const u16* __restrict__ agg2,
                                                  const float* __restrict__ st,
                                                  const float* __restrict__ ga,
                                                  const float* __restrict__ be,
                                                  const float* __restrict__ gs,
                                                  const float* __restrict__ bes,
                                                  const u16* __restrict__ WbT,
                                                  const u16* __restrict__ WsT,
                                                  u16* __restrict__ HW1,
                                                  u16* __restrict__ hw2,
                                                  int Cin) {
  __shared__ u16 smem[17408];      // K-loop: 2x[128][40]; epilogue [128][136]
  __shared__ float lk1[NCOUT], lk2[NCOUT], lcc[NCOUT];
  u16* Wsh = smem;
  u16* Xsh = smem + 128 * 40;
  const int z = blockIdx.z;
  const bool sym = z < GSM;
  const int g = sym ? z : z - GSM;
  const u16* Wmat = sym ? WsT : WbT;
  u16* out = sym ? hw2 : HW1;
  const int n0 = blockIdx.x * 128;
  const int c0 = blockIdx.y * 128;
  const int t = threadIdx.x;
  if (MODE == 1) {
    coef_ld(st, ga, be, gs, bes, lk1, lk2, lcc, t);
    __syncthreads();
  }
  const int wv = t >> 6;
  const int lane = t & 63;
  const int q = lane >> 4, l = lane & 15;
  const int wm = wv >> 1, wn = wv & 1;
  f32x4 zero = {0.f, 0.f, 0.f, 0.f};
  f32x4 acc[4][4];
#pragma unroll
  for (int i = 0; i < 4; ++i)
#pragma unroll
    for (int j = 0; j < 4; ++j) acc[i][j] = zero;
  const int r0 = t >> 2;
  const int seg = (t & 3) * 8;
  const u16* Wg = Wmat + (size_t)(c0 + r0) * Cin + seg;
  const u16* Xplain = sym ? xp : Xbig;
  const u16* Xg = Xplain + ((size_t)g * LNODES + n0 + r0) * Cin + seg;
  const size_t rowd = (size_t)(n0 + r0);
  const size_t nstep = (size_t)LNODES * NCOUT;
  const size_t a1base = sym ? (((size_t)(g * 8) * LNODES + rowd) * NCOUT + seg)
                            : (((size_t)g * LNODES + rowd) * NCOUT + seg);
  const size_t a2base = sym ? (((size_t)g * LNODES + rowd) * NCOUT + seg)
                            : (((size_t)(g >> 3) * LNODES + rowd) * NCOUT + seg);
  for (int k0 = 0; k0 < Cin; k0 += 32) {
    uint4 w0 = *reinterpret_cast<const uint4*>(Wg + k0);
    uint4 w1 = *reinterpret_cast<const uint4*>(Wg + (size_t)64 * Cin + k0);
    uint4 x0, x1;
    if (MODE == 0) {
      x0 = *reinterpret_cast<const uint4*>(Xg + k0);
      x1 = *reinterpret_cast<const uint4*>(Xg + (size_t)64 * Cin + k0);
    } else {
      int kk = k0 + seg;
      // vectorized coef reads: 6x ds_read_b128 instead of 24x ds_read_b32
      float4 K1a = *reinterpret_cast<const float4*>(&lk1[kk]);
      float4 K1b = *reinterpret_cast<const float4*>(&lk1[kk + 4]);
      float4 K2a = *reinterpret_cast<const float4*>(&lk2[kk]);
      float4 K2b = *reinterpret_cast<const float4*>(&lk2[kk + 4]);
      float4 Cca = *reinterpret_cast<const float4*>(&lcc[kk]);
      float4 Ccb = *reinterpret_cast<const float4*>(&lcc[kk + 4]);
      if (!sym) {
        uint4 a1a = *reinterpret_cast<const uint4*>(&AGG1[a1base + k0]);
        uint4 a1b = *reinterpret_cast<const uint4*>(&AGG1[a1base + 64 * (size_t)NCOUT + k0]);
        uint4 a2a = *reinterpret_cast<const uint4*>(&agg2[a2base + k0]);
        uint4 a2b = *reinterpret_cast<const uint4*>(&agg2[a2base + 64 * (size_t)NCOUT + k0]);
        float o0 = fmaxf(K1a.x*blo(a1a.x) + K2a.x*blo(a2a.x) + Cca.x, 0.f);
        float o1 = fmaxf(K1a.y*bhi(a1a.x) + K2a.y*bhi(a2a.x) + Cca.y, 0.f);
        float o2 = fmaxf(K1a.z*blo(a1a.y) + K2a.z*blo(a2a.y) + Cca.z, 0.f);
        float o3 = fmaxf(K1a.w*bhi(a1a.y) + K2a.w*bhi(a2a.y) + Cca.w, 0.f);
        float o4 = fmaxf(K1b.x*blo(a1a.z) + K2b.x*blo(a2a.z) + Ccb.x, 0.f);
        float o5 = fmaxf(K1b.y*bhi(a1a.z) + K2b.y*bhi(a2a.z) + Ccb.y, 0.f);
        float o6 = fmaxf(K1b.z*blo(a1a.w) + K2b.z*blo(a2a.w) + Ccb.z, 0.f);
        float o7 = fmaxf(K1b.w*bhi(a1a.w) + K2b.w*bhi(a2a.w) + Ccb.w, 0.f);
        x0 = {pk2(o0, o1), pk2(o2, o3), pk2(o4, o5), pk2(o6, o7)};
        float p0 = fmaxf(K1a.x*blo(a1b.x) + K2a.x*blo(a2b.x) + Cca.x, 0.f);
        float p1 = fmaxf(K1a.y*bhi(a1b.x) + K2a.y*bhi(a2b.x) + Cca.y, 0.f);
        float p2 = fmaxf(K1a.z*blo(a1b.y) + K2a.z*blo(a2b.y) + Cca.z, 0.f);
        float p3 = fmaxf(K1a.w*bhi(a1b.y) + K2a.w*bhi(a2b.y) + Cca.w, 0.f);
        float p4 = fmaxf(K1b.x*blo(a1b.z) + K2b.x*blo(a2b.z) + Ccb.x, 0.f);
        float p5 = fmaxf(K1b.y*bhi(a1b.z) + K2b.y*bhi(a2b.z) + Ccb.y, 0.f);
        float p6 = fmaxf(K1b.z*blo(a1b.w) + K2b.z*blo(a2b.w) + Ccb.z, 0.f);
        float p7 = fmaxf(K1b.w*bhi(a1b.w) + K2b.w*bhi(a2b.w) + Ccb.w, 0.f);
        x1 = {pk2(p0, p1), pk2(p2, p3), pk2(p4, p5), pk2(p6, p7)};
      } else {
        // sym: pooled A = max(0, max_n(k1*a1_n + (k2*a2 + cc)))
        uint4 a2a = *reinterpret_cast<const uint4*>(&agg2[a2base + k0]);
        uint4 a2b = *reinterpret_cast<const uint4*>(&agg2[a2base + 64 * (size_t)NCOUT + k0]);
        float t0 = K2a.x*blo(a2a.x) + Cca.x, t1 = K2a.y*bhi(a2a.x) + Cca.y;
        float t2 = K2a.z*blo(a2a.y) + Cca.z, t3 = K2a.w*bhi(a2a.y) + Cca.w;
        float t4 = K2b.x*blo(a2a.z) + Ccb.x, t5 = K2b.y*bhi(a2a.z) + Ccb.y;
        float t6 = K2b.z*blo(a2a.w) + Ccb.z, t7 = K2b.w*bhi(a2a.w) + Ccb.w;
        float u0 = K2a.x*blo(a2b.x) + Cca.x, u1 = K2a.y*bhi(a2b.x) + Cca.y;
        float u2 = K2a.z*blo(a2b.y) + Cca.z, u3 = K2a.w*bhi(a2b.y) + Cca.w;
        float u4 = K2b.x*blo(a2b.z) + Ccb.x, u5 = K2b.y*bhi(a2b.z) + Ccb.y;
        float u6 = K2b.z*blo(a2b.w) + Ccb.z, u7 = K2b.w*bhi(a2b.w) + Ccb.w;
        float m0 = 0.f, m1 = 0.f, m2 = 0.f, m3 = 0.f, m4 = 0.f, m5 = 0.f, m6 = 0.f, m7 = 0.f;
        float e0 = 0.f, e1 = 0.f, e2 = 0.f, e3 = 0.f, e4 = 0.f, e5 = 0.f, e6 = 0.f, e7 = 0.f;
#pragma unroll
        for (int n = 0; n < 8; ++n) {
          uint4 a1a = *reinterpret_cast<const uint4*>(&AGG1[a1base + n * nstep + k0]);
          uint4 a1b = *reinterpret_cast<const uint4*>(&AGG1[a1base + n * nstep + 64 * (size_t)NCOUT + k0]);
          m0 = fmaxf(m0, K1a.x*blo(a1a.x) + t0); m1 = fmaxf(m1, K1a.y*bhi(a1a.x) + t1);
          m2 = fmaxf(m2, K1a.z*blo(a1a.y) + t2); m3 = fmaxf(m3, K1a.w*bhi(a1a.y) + t3);
          m4 = fmaxf(m4, K1b.x*blo(a1a.z) + t4); m5 = fmaxf(m5, K1b.y*bhi(a1a.z) + t5);
          m6 = fmaxf(m6, K1b.z*blo(a1a.w) + t6); m7 = fmaxf(m7, K1b.w*bhi(a1a.w) + t7);
          e0 = fmaxf(e0, K1a.x*blo(a1b.x) + u0); e1 = fmaxf(e1, K1a.y*bhi(a1b.x) + u1);
          e2 = fmaxf(e2, K1a.z*blo(a1b.y) + u2); e3 = fmaxf(e3, K1a.w*bhi(a1b.y) + u3);
          e4 = fmaxf(e4, K1b.x*blo(a1b.z) + u4); e5 = fmaxf(e5, K1b.y*bhi(a1b.z) + u5);
          e6 = fmaxf(e6, K1b.z*blo(a1b.w) + u6); e7 = fmaxf(e7, K1b.w*bhi(a1b.w) + u7);
        }
        x0 = {pk2(m0, m1), pk2(m2, m3), pk2(m4, m5), pk2(m6, m7)};
        x1 = {pk2(e0, e1), pk2(e2, e3), pk2(e4, e5), pk2(e6, e7)};
      }
    }
    __syncthreads();
    *reinterpret_cast<uint4*>(&Wsh[r0 * 40 + seg]) = w0;
    *reinterpret_cast<uint4*>(&Wsh[(r0 + 64) * 40 + seg]) = w1;
    *reinterpret_cast<uint4*>(&Xsh[r0 * 40 + seg]) = x0;
    *reinterpret_cast<uint4*>(&Xsh[(r0 + 64) * 40 + seg]) = x1;
    __syncthreads();
    bf16x8 af[4], bx[4];
#pragma unroll
    for (int fi = 0; fi < 4; ++fi)
      af[fi] = *reinterpret_cast<const bf16x8*>(&Wsh[(wm * 64 + fi * 16 + l) * 40 + q * 8]);
#pragma unroll
    for (int fj = 0; fj < 4; ++fj)
      bx[fj] = *reinterpret_cast<const bf16x8*>(&Xsh[(wn * 64 + fj * 16 + l) * 40 + q * 8]);
#pragma unroll
    for (int fi = 0; fi < 4; ++fi)
#pragma unroll
      for (int fj = 0; fj < 4; ++fj)
        acc[fi][fj] = __builtin_amdgcn_mfma_f32_16x16x32_bf16(af[fi], bx[fj], acc[fi][fj], 0, 0, 0);
  }
  __syncthreads();
  u16* Csh = smem;  // [128][136]
#pragma unroll
  for (int fi = 0; fi < 4; ++fi) {
#pragma unroll
    for (int fj = 0; fj < 4; ++fj) {
      int co_l = wm * 64 + fi * 16 + q * 4;
      int nd_l = wn * 64 + fj * 16 + l;
      uint2 pkd = {pk2(acc[fi][fj][0], acc[fi][fj][1]),
                   pk2(acc[fi][fj][2], acc[fi][fj][3])};
      *reinterpret_cast<uint2*>(&Csh[nd_l * 136 + co_l]) = pkd;
    }
  }
  __syncthreads();
#pragma unroll
  for (int p = 0; p < 8; ++p) {
    int idx = p * 256 + t;
    int nd = idx >> 4;
    int c8 = (idx & 15) * 8;
    uint4 v = *reinterpret_cast<const uint4*>(&Csh[nd * 136 + c8]);
    nt_store4(&out[((size_t)g * LNODES + n0 + nd) * NCOUT + c0 + c8], v.x, v.y, v.z, v.w);
  }
}

// ---------------- combined aggregation ----------------
// Big path (1024 blocks): half-wave g-split, lane = 8 channels (uint4).
// Edge loop unrolled x8 (8 gathers in flight), then x4, then singles —
// ascending-e accumulation order preserved (bit-identical numerics).
// Non-temporal stores keep the 36 MB output stream out of the gather L2 set.
__global__ __launch_bounds__(256) void agg_comb_k(const u16* __restrict__ HW1,
                                                  const u16* __restrict__ hw2,
                                                  const int* __restrict__ col,
                                                  const float* __restrict__ wn,
                                                  const int* __restrict__ rp,
                                                  const float* __restrict__ selfn,
                                                  u16* __restrict__ AGG1,
                                                  u16* __restrict__ agg2,
                                                  float* __restrict__ st) {
  __shared__ float lsum[8][NCOUT], lsq[8][NCOUT];
  const int bid = blockIdx.x;
  const int t = threadIdx.x;
  const int wv = t >> 6;
  float* sumO;
  float* sqO;
  int shard;
  if (bid < 1024) {
    int slot = bid >> 3;
    int chunk = slot & 63;
    int g0 = (bid & 7) + 8 * (slot >> 6);
    const int d0 = chunk * ND;
    const int h = (t >> 5) & 1;   // half-wave: which graph copy
    const int ch = (t & 31) * 8;  // channel octet
    const u16* baseh = HW1 + (size_t)(g0 + 16 * h) * LNODES * NCOUT;
    u16* outh = AGG1 + (size_t)(g0 + 16 * h) * LNODES * NCOUT;
    float s0 = 0.f, s1 = 0.f, s2 = 0.f, s3 = 0.f, s4 = 0.f, s5 = 0.f, s6 = 0.f, s7 = 0.f;
    float q0 = 0.f, q1 = 0.f, q2 = 0.f, q3 = 0.f, q4 = 0.f, q5 = 0.f, q6 = 0.f, q7 = 0.f;
    for (int i = wv; i < ND; i += 4) {
      int d = d0 + i;
      int e0 = rp[d], e1 = rp[d + 1];
      float sw = selfn[d];
      uint4 u = *reinterpret_cast<const uint4*>(&baseh[(size_t)d * NCOUT + ch]);
      float a0 = sw * blo(u.x), a1 = sw * bhi(u.x), a2 = sw * blo(u.y), a3 = sw * bhi(u.y);
      float a4 = sw * blo(u.z), a5 = sw * bhi(u.z), a6 = sw * blo(u.w), a7 = sw * bhi(u.w);
      int e = e0;
      const int e8 = e0 + ((e1 - e0) & ~7);
      for (; e < e8; e += 8) {
        int i0 = col[e + 0], i1 = col[e + 1], i2 = col[e + 2], i3 = col[e + 3];
        int i4 = col[e + 4], i5 = col[e + 5], i6 = col[e + 6], i7 = col[e + 7];
        float w0 = wn[e + 0], w1 = wn[e + 1], w2 = wn[e + 2], w3 = wn[e + 3];
        float w4 = wn[e + 4], w5 = wn[e + 5], w6 = wn[e + 6], w7 = wn[e + 7];
        uint4 v0 = *reinterpret_cast<const uint4*>(&baseh[(size_t)i0 * NCOUT + ch]);
        uint4 v1 = *reinterpret_cast<const uint4*>(&baseh[(size_t)i1 * NCOUT + ch]);
        uint4 v2 = *reinterpret_cast<const uint4*>(&baseh[(size_t)i2 * NCOUT + ch]);
        uint4 v3 = *reinterpret_cast<const uint4*>(&baseh[(size_t)i3 * NCOUT + ch]);
        uint4 v4 = *reinterpret_cast<const uint4*>(&baseh[(size_t)i4 * NCOUT + ch]);
        uint4 v5 = *reinterpret_cast<const uint4*>(&baseh[(size_t)i5 * NCOUT + ch]);
        uint4 v6 = *reinterpret_cast<const uint4*>(&baseh[(size_t)i6 * NCOUT + ch]);
        uint4 v7 = *reinterpret_cast<const uint4*>(&baseh[(size_t)i7 * NCOUT + ch]);
        a0 += w0 * blo(v0.x); a1 += w0 * bhi(v0.x); a2 += w0 * blo(v0.y); a3 += w0 * bhi(v0.y);
        a4 += w0 * blo(v0.z); a5 += w0 * bhi(v0.z); a6 += w0 * blo(v0.w); a7 += w0 * bhi(v0.w);
        a0 += w1 * blo(v1.x); a1 += w1 * bhi(v1.x); a2 += w1 * blo(v1.y); a3 += w1 * bhi(v1.y);
        a4 += w1 * blo(v1.z); a5 += w1 * bhi(v1.z); a6 += w1 * blo(v1.w); a7 += w1 * bhi(v1.w);
        a0 += w2 * blo(v2.x); a1 += w2 * bhi(v2.x); a2 += w2 * blo(v2.y); a3 += w2 * bhi(v2.y);
        a4 += w2 * blo(v2.z); a5 += w2 * bhi(v2.z); a6 += w2 * blo(v2.w); a7 += w2 * bhi(v2.w);
        a0 += w3 * blo(v3.x); a1 += w3 * bhi(v3.x); a2 += w3 * blo(v3.y); a3 += w3 * bhi(v3.y);
        a4 += w3 * blo(v3.z); a5 += w3 * bhi(v3.z); a6 += w3 * blo(v3.w); a7 += w3 * bhi(v3.w);
        a0 += w4 * blo(v4.x); a1 += w4 * bhi(v4.x); a2 += w4 * blo(v4.y); a3 += w4 * bhi(v4.y);
        a4 += w4 * blo(v4.z); a5 += w4 * bhi(v4.z); a6 += w4 * blo(v4.w); a7 += w4 * bhi(v4.w);
        a0 += w5 * blo(v5.x); a1 += w5 * bhi(v5.x); a2 += w5 * blo(v5.y); a3 += w5 * bhi(v5.y);
        a4 += w5 * blo(v5.z); a5 += w5 * bhi(v5.z); a6 += w5 * blo(v5.w); a7 += w5 * bhi(v5.w);
        a0 += w6 * blo(v6.x); a1 += w6 * bhi(v6.x); a2 += w6 * blo(v6.y); a3 += w6 * bhi(v6.y);
        a4 += w6 * blo(v6.z); a5 += w6 * bhi(v6.z); a6 += w6 * blo(v6.w); a7 += w6 * bhi(v6.w);
        a0 += w7 * blo(v7.x); a1 += w7 * bhi(v7.x); a2 += w7 * blo(v7.y); a3 += w7 * bhi(v7.y);
        a4 += w7 * blo(v7.z); a5 += w7 * bhi(v7.z); a6 += w7 * blo(v7.w); a7 += w7 * bhi(v7.w);
      }
      const int e4 = e0 + ((e1 - e0) & ~3);
      for (; e < e4; e += 4) {
        int i0 = col[e + 0], i1 = col[e + 1], i2 = col[e + 2], i3 = col[e + 3];
        float w0 = wn[e + 0], w1 = wn[e + 1], w2 = wn[e + 2], w3 = wn[e + 3];
        uint4 v0 = *reinterpret_cast<const uint4*>(&baseh[(size_t)i0 * NCOUT + ch]);
        uint4 v1 = *reinterpret_cast<const uint4*>(&baseh[(size_t)i1 * NCOUT + ch]);
        uint4 v2 = *reinterpret_cast<const uint4*>(&baseh[(size_t)i2 * NCOUT + ch]);
        uint4 v3 = *reinterpret_cast<const uint4*>(&baseh[(size_t)i3 * NCOUT + ch]);
        a0 += w0 * blo(v0.x); a1 += w0 * bhi(v0.x); a2 += w0 * blo(v0.y); a3 += w0 * bhi(v0.y);
        a4 += w0 * blo(v0.z); a5 += w0 * bhi(v0.z); a6 += w0 * blo(v0.w); a7 += w0 * bhi(v0.w);
        a0 += w1 * blo(v1.x); a1 += w1 * bhi(v1.x); a2 += w1 * blo(v1.y); a3 += w1 * bhi(v1.y);
        a4 += w1 * blo(v1.z); a5 += w1 * bhi(v1.z); a6 += w1 * blo(v1.w); a7 += w1 * bhi(v1.w);
        a0 += w2 * blo(v2.x); a1 += w2 * bhi(v2.x); a2 += w2 * blo(v2.y); a3 += w2 * bhi(v2.y);
        a4 += w2 * blo(v2.z); a5 += w2 * bhi(v2.z); a6 += w2 * blo(v2.w); a7 += w2 * bhi(v2.w);
        a0 += w3 * blo(v3.x); a1 += w3 * bhi(v3.x); a2 += w3 * blo(v3.y); a3 += w3 * bhi(v3.y);
        a4 += w3 * blo(v3.z); a5 += w3 * bhi(v3.z); a6 += w3 * blo(v3.w); a7 += w3 * bhi(v3.w);
      }
      for (; e < e1; ++e) {
        int ci = col[e];
        float w = wn[e];
        uint4 v = *reinterpret_cast<const uint4*>(&baseh[(size_t)ci * NCOUT + ch]);
        a0 += w * blo(v.x); a1 += w * bhi(v.x); a2 += w * blo(v.y); a3 += w * bhi(v.y);
        a4 += w * blo(v.z); a5 += w * bhi(v.z); a6 += w * blo(v.w); a7 += w * bhi(v.w);
      }
      nt_store4(&outh[(size_t)d * NCOUT + ch],
                pk2(a0, a1), pk2(a2, a3), pk2(a4, a5), pk2(a6, a7));
      s0 += a0; s1 += a1; s2 += a2; s3 += a3; s4 += a4; s5 += a5; s6 += a6; s7 += a7;
      q0 += a0 * a0; q1 += a1 * a1; q2 += a2 * a2; q3 += a3 * a3;
      q4 += a4 * a4; q5 += a5 * a5; q6 += a6 * a6; q7 += a7 * a7;
    }
    int row = wv * 2 + h;
    float4 sa = {s0, s1, s2, s3}, sb = {s4, s5, s6, s7};
    float4 qa = {q0, q1, q2, q3}, qb = {q4, q5, q6, q7};
    *reinterpret_cast<float4*>(&lsum[row][ch]) = sa;
    *reinterpret_cast<float4*>(&lsum[row][ch + 4]) = sb;
    *reinterpret_cast<float4*>(&lsq[row][ch]) = qa;
    *reinterpret_cast<float4*>(&lsq[row][ch + 4]) = qb;
    sumO = st; sqO = st + 2048; shard = (bid & 7) * NCOUT;
  } else {
    int b2 = bid - 1024;
    int g = b2 & (GSM - 1);
    int chunk = b2 >> 2;
    const int d0 = chunk * ND;
    const int lc = (t & 63) * 4;
    const u16* base = hw2 + (size_t)g * LNODES * NCOUT;
    float4 s = {0.f, 0.f, 0.f, 0.f}, qq = {0.f, 0.f, 0.f, 0.f};
    for (int i = wv; i < ND; i += 4) {
      int d = d0 + i;
      int e0 = rp[d], e1 = rp[d + 1];
      float sw = selfn[d];
      uint2 u = *reinterpret_cast<const uint2*>(&base[(size_t)d * NCOUT + lc]);
      float4 a = {sw * blo(u.x), sw * bhi(u.x), sw * blo(u.y), sw * bhi(u.y)};
      int e = e0;
      const int e4 = e0 + ((e1 - e0) & ~3);
      for (; e < e4; e += 4) {
        int i0 = col[e + 0], i1 = col[e + 1], i2 = col[e + 2], i3 = col[e + 3];
        float w0 = wn[e + 0], w1 = wn[e + 1], w2 = wn[e + 2], w3 = wn[e + 3];
        uint2 v0 = *reinterpret_cast<const uint2*>(&base[(size_t)i0 * NCOUT + lc]);
        uint2 v1 = *reinterpret_cast<const uint2*>(&base[(size_t)i1 * NCOUT + lc]);
        uint2 v2 = *reinterpret_cast<const uint2*>(&base[(size_t)i2 * NCOUT + lc]);
        uint2 v3 = *reinterpret_cast<const uint2*>(&base[(size_t)i3 * NCOUT + lc]);
        a.x += w0 * blo(v0.x); a.y += w0 * bhi(v0.x); a.z += w0 * blo(v0.y); a.w += w0 * bhi(v0.y);
        a.x += w1 * blo(v1.x); a.y += w1 * bhi(v1.x); a.z += w1 * blo(v1.y); a.w += w1 * bhi(v1.y);
        a.x += w2 * blo(v2.x); a.y += w2 * bhi(v2.x); a.z += w2 * blo(v2.y); a.w += w2 * bhi(v2.y);
        a.x += w3 * blo(v3.x); a.y += w3 * bhi(v3.x); a.z += w3 * blo(v3.y); a.w += w3 * bhi(v3.y);
      }
      for (; e < e1; ++e) {
        float w = wn[e];
        uint2 v = *reinterpret_cast<const uint2*>(&base[(size_t)col[e] * NCOUT + lc]);
        a.x += w * blo(v.x); a.y += w * bhi(v.x); a.z += w * blo(v.y); a.w += w * bhi(v.y);
      }
      nt_store2(&agg2[((size_t)g * LNODES + d) * NCOUT + lc], pk2(a.x, a.y), pk2(a.z, a.w));
      s.x += a.x; s.y += a.y; s.z += a.z; s.w += a.w;
      qq.x += a.x * a.x; qq.y += a.y * a.y; qq.z += a.z * a.z; qq.w += a.w * a.w;
    }
    *reinterpret_cast<float4*>(&lsum[wv][lc]) = s;
    *reinterpret_cast<float4*>(&lsq[wv][lc]) = qq;
    float4 z4 = {0.f, 0.f, 0.f, 0.f};
    *reinterpret_cast<float4*>(&lsum[wv + 4][lc]) = z4;
    *reinterpret_cast<float4*>(&lsq[wv + 4][lc]) = z4;
    sumO = st + 4096; sqO = st + 6144; shard = (b2 & 7) * NCOUT;
  }
  __syncthreads();
  float ts = 0.f, tq = 0.f;
#pragma unroll
  for (int r = 0; r < 8; ++r) {
    ts += lsum[r][t];
    tq += lsq[r][t];
  }
  atomicAdd(&sumO[shard + t], ts);
  atomicAdd(&sqO[shard + t], tq);
}

// ---------------- layer 2: fuse + transpose to channel-major fp32 d_out ----------------
__global__ __launch_bounds__(256) void fuse_tr_bf_k(const u16* __restrict__ A1,
                                                    const u16* __restrict__ A2,
                                                    const float* __restrict__ st,
                                                    const float* __restrict__ ga,
                                                    const float* __restrict__ be,
                                                    const float* __restrict__ gs,
                                                    const float* __restrict__ bes,
                                                    float* __restrict__ O) {
  __shared__ float T[64][65];  // [node_local][co_local]
  __shared__ float lk1[NCOUT], lk2[NCOUT], lcc[NCOUT];
  const int g = blockIdx.z;
  const int d0 = blockIdx.x * 64;
  const int c0 = blockIdx.y * 64;
  const int b = g >> 3;
  const int t = threadIdx.x;
  coef_ld(st, ga, be, gs, bes, lk1, lk2, lcc, t);
  __syncthreads();
  const int tr = t >> 4;
  const int tc = (t & 15) * 4;
#pragma unroll
  for (int p = 0; p < 4; ++p) {
    int d = d0 + tr + p * 16;
    uint2 a1 = *reinterpret_cast<const uint2*>(&A1[((size_t)g * LNODES + d) * NCOUT + c0 + tc]);
    uint2 a2 = *reinterpret_cast<const uint2*>(&A2[((size_t)b * LNODES + d) * NCOUT + c0 + tc]);
    int cb = c0 + tc;
    T[tr + p * 16][tc + 0] = fmaxf(lk1[cb+0] * blo(a1.x) + lk2[cb+0] * blo(a2.x) + lcc[cb+0], 0.f);
    T[tr + p * 16][tc + 1] = fmaxf(lk1[cb+1] * bhi(a1.x) + lk2[cb+1] * bhi(a2.x) + lcc[cb+1], 0.f);
    T[tr + p * 16][tc + 2] = fmaxf(lk1[cb+2] * blo(a1.y) + lk2[cb+2] * blo(a2.y) + lcc[cb+2], 0.f);
    T[tr + p * 16][tc + 3] = fmaxf(lk1[cb+3] * bhi(a1.y) + lk2[cb+3] * bhi(a2.y) + lcc[cb+3], 0.f);
  }
  __syncthreads();
#pragma unroll
  for (int p = 0; p < 4; ++p) {
    int c = tr + p * 16;
    nt_storef4(&O[((size_t)g * NCOUT + c0 + c) * LNODES + d0 + tc],
               T[tc + 0][c], T[tc + 1][c], T[tc + 2][c], T[tc + 3][c]);
  }
}

// ---------------- launch ----------------

extern "C" void kernel_launch(void* const* d_in, const int* in_sizes, int n_in,
                              void* d_out, int out_size, void* d_ws, size_t ws_size,
                              hipStream_t stream) {
  const float* x_in = (const float*)d_in[0];
  const int* ei = (const int*)d_in[1];
  const float* W[3]   = {(const float*)d_in[2],  (const float*)d_in[4],  (const float*)d_in[6]};
  const float* Wsym[3]= {(const float*)d_in[8],  (const float*)d_in[10], (const float*)d_in[12]};
  const float* ga[3]  = {(const float*)d_in[14], (const float*)d_in[16], (const float*)d_in[18]};
  const float* be[3]  = {(const float*)d_in[15], (const float*)d_in[17], (const float*)d_in[19]};
  const float* gs[3]  = {(const float*)d_in[20], (const float*)d_in[22], (const float*)d_in[24]};
  const float* bes[3] = {(const float*)d_in[21], (const float*)d_in[23], (const float*)d_in[25]};

  const size_t EBIG = (size_t)GBIG * LNODES * NCOUT;  // 16.7M elems
  const size_t ESM = (size_t)GSM * LNODES * NCOUT;
  char* p = (char*)d_ws;
  u16* XT0  = (u16*)p; p += (size_t)GBIG * LNODES * 128 * 2;  // 16 MiB layer-0 input
  u16* AGG1 = (u16*)p; p += EBIG * 2;   // 32 MiB
  u16* agg2 = (u16*)p; p += ESM * 2;    // 4 MiB
  u16* xp   = (u16*)p; p += (size_t)GSM * LNODES * 128 * 2;   // 2 MiB (layer-0 only)
  u16* hw2  = (u16*)p; p += ESM * 2;    // 4 MiB
  u16* WbT[3], *WsT[3];
  for (int i = 0; i < 3; ++i) { WbT[i] = (u16*)p; p += NCOUT * NCOUT * 2; }
  for (int i = 0; i < 3; ++i) { WsT[i] = (u16*)p; p += NCOUT * NCOUT * 2; }
  int*   rp   = (int*)p;   p += 2064 * 4;
  float* dis  = (float*)p; p += LNODES * 4;
  float* selfn= (float*)p; p += LNODES * 4;
  char* zbase = p;
  float* deg  = (float*)p; p += LNODES * 4;
  int*   cnt  = (int*)p;   p += LNODES * 4;
  int*   fillc= (int*)p;   p += LNODES * 4;
  int*   col  = (int*)p;   p += (NEDGE + 8) * 4;  // padded, zeroed
  float* wn   = (float*)p; p += (NEDGE + 8) * 4;  // padded, zeroed
  float* stats= (float*)p; p += 3 * 4 * 2048 * 4; // [3 layers][sum1|sq1|sum2|sq2][8][256]
  size_t zsize = (size_t)(p - zbase);

  u16* HW1 = (u16*)d_out;  // big GEMM out in d_out (dead by fuse_tr time)
  float* stL[3] = {stats, stats + 8192, stats + 16384};

  // ---- setup: CSR + weights + input transpose + layer-0 pool ----
  hipMemsetAsync(zbase, 0, zsize, stream);
  count_deg_k<<<NEDGE / 256, 256, 0, stream>>>(ei, deg, cnt);
  dis_k<<<LNODES / 256, 256, 0, stream>>>(deg, dis, selfn);
  scan_k<<<1, 256, 0, stream>>>(cnt, rp);
  fill_k<<<NEDGE / 256, 256, 0, stream>>>(ei, rp, fillc, dis, col, wn);
  WCvt wc;
  for (int i = 0; i < 3; ++i) {
    wc.src[i] = W[i];     wc.dst[i] = WbT[i];     wc.ci[i] = (i == 0) ? 128 : 256;
    wc.src[3 + i] = Wsym[i]; wc.dst[3 + i] = WsT[i]; wc.ci[3 + i] = (i == 0) ? 128 : 256;
  }
  cvtw_all_k<<<dim3(4, 4, 6), 256, 0, stream>>>(wc);
  trans_k<<<dim3(LNODES / 64, 128 / 64, GBIG), 256, 0, stream>>>(x_in, XT0, 128);
  pool_bf_k<<<GSM * 128 * LNODES / 8 / 256, 256, 0, stream>>>(XT0, xp, 128 * LNODES);

  dim3 ggrid(LNODES / 128, NCOUT / 128, GBIG + GSM);
  for (int l = 0; l < 3; ++l) {
    if (l == 0) {
      gemm_all_k<0><<<ggrid, 256, 0, stream>>>(XT0, xp, AGG1, agg2, nullptr,
                                               nullptr, nullptr, nullptr, nullptr,
                                               WbT[l], WsT[l], HW1, hw2, 128);
    } else {
      gemm_all_k<1><<<ggrid, 256, 0, stream>>>(XT0, xp, AGG1, agg2, stL[l - 1],
                                               ga[l - 1], be[l - 1], gs[l - 1], bes[l - 1],
                                               WbT[l], WsT[l], HW1, hw2, NCOUT);
    }
    agg_comb_k<<<1280, 256, 0, stream>>>(HW1, hw2, col, wn, rp, selfn,
                                         AGG1, agg2, stL[l]);
  }
  fuse_tr_bf_k<<<dim3(LNODES / 64, NCOUT / 64, GBIG), 256, 0, stream>>>(
      AGG1, agg2, stL[2], ga[2], be[2], gs[2], bes[2], (float*)d_out);
}

// Round 14
// 375.205 us; speedup vs baseline: 1.0857x; 1.0857x over previous
//
#include <hip/hip_runtime.h>
#include <math.h>

#define LNODES 2048
#define NEDGE 16384
#define GBIG 32
#define GSM 4
#define NCOUT 256
#define BN_EPS 1e-5f
#define ND 32  // dst nodes per agg block

typedef unsigned short u16;
typedef __attribute__((ext_vector_type(8))) short bf16x8;
typedef __attribute__((ext_vector_type(4))) float f32x4;
typedef __attribute__((ext_vector_type(4))) unsigned u32x4;
typedef __attribute__((ext_vector_type(2))) unsigned u32x2;

__device__ __forceinline__ unsigned pk2(float a, float b) {  // a->lo, b->hi
  unsigned ua = __float_as_uint(a); ua += 0x7fffu + ((ua >> 16) & 1u);
  unsigned ub = __float_as_uint(b); ub += 0x7fffu + ((ub >> 16) & 1u);
  return (ua >> 16) | (ub & 0xffff0000u);
}
__device__ __forceinline__ float blo(unsigned u) { return __uint_as_float(u << 16); }
__device__ __forceinline__ float bhi(unsigned u) { return __uint_as_float(u & 0xffff0000u); }

__device__ __forceinline__ void nt_store4(void* p, unsigned a, unsigned b,
                                          unsigned c, unsigned d) {
  u32x4 v = {a, b, c, d};
  __builtin_nontemporal_store(v, reinterpret_cast<u32x4*>(p));
}
__device__ __forceinline__ void nt_store2(void* p, unsigned a, unsigned b) {
  u32x2 v = {a, b};
  __builtin_nontemporal_store(v, reinterpret_cast<u32x2*>(p));
}
__device__ __forceinline__ void nt_storef4(void* p, float a, float b, float c, float d) {
  f32x4 v = {a, b, c, d};
  __builtin_nontemporal_store(v, reinterpret_cast<f32x4*>(p));
}

// ---------------- setup: degree, dis, CSR ----------------

__global__ __launch_bounds__(256) void count_deg_k(const int* __restrict__ ei,
                                                   float* __restrict__ deg,
                                                   int* __restrict__ cnt) {
  int e = blockIdx.x * 256 + threadIdx.x;
  if (e < NEDGE) {
    int d = ei[NEDGE + e];
    atomicAdd(&deg[d], 1.0f);
    atomicAdd(&cnt[d], 1);
  }
}

__global__ __launch_bounds__(256) void dis_k(const float* __restrict__ deg,
                                             float* __restrict__ dis,
                                             float* __restrict__ selfn) {
  int i = blockIdx.x * 256 + threadIdx.x;
  if (i < LNODES) {
    float di = rsqrtf(deg[i] + 2.0f);  // improved=True self loop weight 2
    dis[i] = di;
    selfn[i] = 2.0f * di * di;
  }
}

__global__ __launch_bounds__(256) void scan_k(const int* __restrict__ cnt,
                                              int* __restrict__ rp) {
  __shared__ int part[256];
  int t = threadIdx.x;
  int base = t * 8;
  int loc[8];
  int s = 0;
#pragma unroll
  for (int j = 0; j < 8; ++j) { loc[j] = s; s += cnt[base + j]; }
  part[t] = s;
  __syncthreads();
  for (int off = 1; off < 256; off <<= 1) {
    int v = (t >= off) ? part[t - off] : 0;
    __syncthreads();
    part[t] += v;
    __syncthreads();
  }
  int excl = (t == 0) ? 0 : part[t - 1];
#pragma unroll
  for (int j = 0; j < 8; ++j) rp[base + j] = excl + loc[j];
  if (t == 255) rp[LNODES] = part[255];
}

__global__ __launch_bounds__(256) void fill_k(const int* __restrict__ ei,
                                              const int* __restrict__ rp,
                                              int* __restrict__ fillc,
                                              const float* __restrict__ dis,
                                              int* __restrict__ col,
                                              float* __restrict__ wn) {
  int e = blockIdx.x * 256 + threadIdx.x;
  if (e < NEDGE) {
    int s = ei[e], d = ei[NEDGE + e];
    int pos = rp[d] + atomicAdd(&fillc[d], 1);
    col[pos] = s;
    wn[pos] = dis[s] * dis[d];
  }
}

// ---------------- x [G][Cin][L] f32 -> XT [G][L][Cin] bf16 ----------------
__global__ __launch_bounds__(256) void trans_k(const float* __restrict__ X,
                                               u16* __restrict__ XT, int Cin) {
  __shared__ float T[64][65];  // [ci_local][node_local]
  const int g = blockIdx.z;
  const int n0 = blockIdx.x * 64;
  const int c0 = blockIdx.y * 64;
  const int tr = threadIdx.x >> 4;
  const int tc = (threadIdx.x & 15) * 4;
#pragma unroll
  for (int p = 0; p < 4; ++p) {
    int ci = c0 + tr + p * 16;
    float4 v = *reinterpret_cast<const float4*>(&X[((size_t)g * Cin + ci) * LNODES + n0 + tc]);
    T[tr + p * 16][tc + 0] = v.x; T[tr + p * 16][tc + 1] = v.y;
    T[tr + p * 16][tc + 2] = v.z; T[tr + p * 16][tc + 3] = v.w;
  }
  __syncthreads();
#pragma unroll
  for (int p = 0; p < 4; ++p) {
    int nd = tr + p * 16;
    uint2 o = {pk2(T[tc + 0][nd], T[tc + 1][nd]), pk2(T[tc + 2][nd], T[tc + 3][nd])};
    *reinterpret_cast<uint2*>(&XT[((size_t)g * LNODES + n0 + nd) * Cin + c0 + tc]) = o;
  }
}

// ---------------- all 6 weights: W [Ci][256] f32 -> WT [256][Ci] bf16, one launch ----------------
struct WCvt {
  const float* src[6];
  u16* dst[6];
  int ci[6];
};
__global__ __launch_bounds__(256) void cvtw_all_k(WCvt wp) {
  __shared__ float T[64][65];
  const int w = blockIdx.z;
  const int Ci = wp.ci[w];
  const int ci0 = blockIdx.y * 64;
  if (ci0 >= Ci) return;
  const float* W = wp.src[w];
  u16* WT = wp.dst[w];
  const int co0 = blockIdx.x * 64;
  const int tr = threadIdx.x >> 4;
  const int tc = (threadIdx.x & 15) * 4;
#pragma unroll
  for (int p = 0; p < 4; ++p) {
    int ci = ci0 + tr + p * 16;
    float4 v = *reinterpret_cast<const float4*>(&W[(size_t)ci * NCOUT + co0 + tc]);
    T[tr + p * 16][tc + 0] = v.x; T[tr + p * 16][tc + 1] = v.y;
    T[tr + p * 16][tc + 2] = v.z; T[tr + p * 16][tc + 3] = v.w;
  }
  __syncthreads();
#pragma unroll
  for (int p = 0; p < 4; ++p) {
    int co = tr + p * 16;
    uint2 o = {pk2(T[tc + 0][co], T[tc + 1][co]), pk2(T[tc + 2][co], T[tc + 3][co])};
    *reinterpret_cast<uint2*>(&WT[(size_t)(co0 + co) * Ci + ci0 + tc]) = o;
  }
}

// ---------------- layer-0 max-pool over N=8 (raw bf16 input) ----------------
__global__ __launch_bounds__(256) void pool_bf_k(const u16* __restrict__ X,
                                                 u16* __restrict__ XP, int per) {
  int i = blockIdx.x * 256 + threadIdx.x;
  size_t f = (size_t)i * 8;
  int b = (int)(f / per);
  size_t rem = f - (size_t)b * per;
  const u16* base = X + (size_t)b * 8 * per + rem;
  uint4 u = *reinterpret_cast<const uint4*>(base);
  float m0 = blo(u.x), m1 = bhi(u.x), m2 = blo(u.y), m3 = bhi(u.y);
  float m4 = blo(u.z), m5 = bhi(u.z), m6 = blo(u.w), m7 = bhi(u.w);
#pragma unroll
  for (int j = 1; j < 8; ++j) {
    uint4 v = *reinterpret_cast<const uint4*>(base + (size_t)j * per);
    m0 = fmaxf(m0, blo(v.x)); m1 = fmaxf(m1, bhi(v.x));
    m2 = fmaxf(m2, blo(v.y)); m3 = fmaxf(m3, bhi(v.y));
    m4 = fmaxf(m4, blo(v.z)); m5 = fmaxf(m5, bhi(v.z));
    m6 = fmaxf(m6, blo(v.w)); m7 = fmaxf(m7, bhi(v.w));
  }
  uint4 o = {pk2(m0, m1), pk2(m2, m3), pk2(m4, m5), pk2(m6, m7)};
  *reinterpret_cast<uint4*>(XP + (size_t)b * per + rem) = o;
}

// ---------------- coef reduction helper: shards -> LDS k1/k2/cc ----------------
// st layout per layer: sum1[8][256] | sq1 | sum2 | sq2 (floats, 8192 total)
__device__ __forceinline__ void coef_ld(const float* __restrict__ st,
                                        const float* __restrict__ ga,
                                        const float* __restrict__ be,
                                        const float* __restrict__ gs,
                                        const float* __restrict__ bes,
                                        float* lk1, float* lk2, float* lcc, int t) {
  float sA = 0.f, qA = 0.f, sB = 0.f, qB = 0.f;
#pragma unroll
  for (int x = 0; x < 8; ++x) {
    sA += st[x * NCOUT + t];
    qA += st[2048 + x * NCOUT + t];
    sB += st[4096 + x * NCOUT + t];
    qB += st[6144 + x * NCOUT + t];
  }
  const float c1 = (float)(GBIG * LNODES), c2 = (float)(GSM * LNODES);
  float mA = sA / c1;
  float vA = qA / c1 - mA * mA;
  float kA = ga[t] * rsqrtf(vA + BN_EPS);
  float mB = sB / c2;
  float vB = qB / c2 - mB * mB;
  float kB = gs[t] * rsqrtf(vB + BN_EPS);
  lk1[t] = kA;
  lk2[t] = kB;
  lcc[t] = be[t] - kA * mA + bes[t] - kB * mB;
}

// ---------------- bf16 MFMA GEMM, combined sym+big, fused BN(+pool) staging ----------------
template <int MODE>
__global__ __launch_bounds__(256) void gemm_all_k(const u16* __restrict__ Xbig,
                                                  const u16* __restrict__ xp,
                                                  const u16* __restrict__ AGG1,
                                                  const u16* __restrict__ agg2,
                                                  const float* __restrict__ st,
                                                  const float* __restrict__ ga,
                                                  const float* __restrict__ be,
                                                  const float* __restrict__ gs,
                                                  const float* __restrict__ bes,
                                                  const u16* __restrict__ WbT,
                                                  const u16* __restrict__ WsT,
                                                  u16* __restrict__ HW1,
                                                  u16* __restrict__ hw2,
                                                  int Cin) {
  __shared__ u16 smem[17408];      // K-loop: 2x[128][40]; epilogue [128][136]
  __shared__ float lk1[NCOUT], lk2[NCOUT], lcc[NCOUT];
  u16* Wsh = smem;
  u16* Xsh = smem + 128 * 40;
  const int z = blockIdx.z;
  const bool sym = z < GSM;
  const int g = sym ? z : z - GSM;
  const u16* Wmat = sym ? WsT : WbT;
  u16* out = sym ? hw2 : HW1;
  const int n0 = blockIdx.x * 128;
  const int c0 = blockIdx.y * 128;
  const int t = threadIdx.x;
  if (MODE == 1) {
    coef_ld(st, ga, be, gs, bes, lk1, lk2, lcc, t);
    __syncthreads();
  }
  const int wv = t >> 6;
  const int lane = t & 63;
  const int q = lane >> 4, l = lane & 15;
  const int wm = wv >> 1, wn = wv & 1;
  f32x4 zero = {0.f, 0.f, 0.f, 0.f};
  f32x4 acc[4][4];
#pragma unroll
  for (int i = 0; i < 4; ++i)
#pragma unroll
    for (int j = 0; j < 4; ++j) acc[i][j] = zero;
  const int r0 = t >> 2;
  const int seg = (t & 3) * 8;
  const u16* Wg = Wmat + (size_t)(c0 + r0) * Cin + seg;
  const u16* Xplain = sym ? xp : Xbig;
  const u16* Xg = Xplain + ((size_t)g * LNODES + n0 + r0) * Cin + seg;
  const size_t rowd = (size_t)(n0 + r0);
  const size_t nstep = (size_t)LNODES * NCOUT;
  const size_t a1base = sym ? (((size_t)(g * 8) * LNODES + rowd) * NCOUT + seg)
                            : (((size_t)g * LNODES + rowd) * NCOUT + seg);
  const size_t a2base = sym ? (((size_t)g * LNODES + rowd) * NCOUT + seg)
                            : (((size_t)(g >> 3) * LNODES + rowd) * NCOUT + seg);
  for (int k0 = 0; k0 < Cin; k0 += 32) {
    uint4 w0 = *reinterpret_cast<const uint4*>(Wg + k0);
    uint4 w1 = *reinterpret_cast<const uint4*>(Wg + (size_t)64 * Cin + k0);
    uint4 x0, x1;
    if (MODE == 0) {
      x0 = *reinterpret_cast<const uint4*>(Xg + k0);
      x1 = *reinterpret_cast<const uint4*>(Xg + (size_t)64 * Cin + k0);
    } else {
      int kk = k0 + seg;
      // vectorized coef reads: 6x ds_read_b128 instead of 24x ds_read_b32
      float4 K1a = *reinterpret_cast<const float4*>(&lk1[kk]);
      float4 K1b = *reinterpret_cast<const float4*>(&lk1[kk + 4]);
      float4 K2a = *reinterpret_cast<const float4*>(&lk2[kk]);
      float4 K2b = *reinterpret_cast<const float4*>(&lk2[kk + 4]);
      float4 Cca = *reinterpret_cast<const float4*>(&lcc[kk]);
      float4 Ccb = *reinterpret_cast<const float4*>(&lcc[kk + 4]);
      if (!sym) {
        uint4 a1a = *reinterpret_cast<const uint4*>(&AGG1[a1base + k0]);
        uint4 a1b = *reinterpret_cast<const uint4*>(&AGG1[a1base + 64 * (size_t)NCOUT + k0]);
        uint4 a2a = *reinterpret_cast<const uint4*>(&agg2[a2base + k0]);
        uint4 a2b = *reinterpret_cast<const uint4*>(&agg2[a2base + 64 * (size_t)NCOUT + k0]);
        float o0 = fmaxf(K1a.x*blo(a1a.x) + K2a.x*blo(a2a.x) + Cca.x, 0.f);
        float o1 = fmaxf(K1a.y*bhi(a1a.x) + K2a.y*bhi(a2a.x) + Cca.y, 0.f);
        float o2 = fmaxf(K1a.z*blo(a1a.y) + K2a.z*blo(a2a.y) + Cca.z, 0.f);
        float o3 = fmaxf(K1a.w*bhi(a1a.y) + K2a.w*bhi(a2a.y) + Cca.w, 0.f);
        float o4 = fmaxf(K1b.x*blo(a1a.z) + K2b.x*blo(a2a.z) + Ccb.x, 0.f);
        float o5 = fmaxf(K1b.y*bhi(a1a.z) + K2b.y*bhi(a2a.z) + Ccb.y, 0.f);
        float o6 = fmaxf(K1b.z*blo(a1a.w) + K2b.z*blo(a2a.w) + Ccb.z, 0.f);
        float o7 = fmaxf(K1b.w*bhi(a1a.w) + K2b.w*bhi(a2a.w) + Ccb.w, 0.f);
        x0 = {pk2(o0, o1), pk2(o2, o3), pk2(o4, o5), pk2(o6, o7)};
        float p0 = fmaxf(K1a.x*blo(a1b.x) + K2a.x*blo(a2b.x) + Cca.x, 0.f);
        float p1 = fmaxf(K1a.y*bhi(a1b.x) + K2a.y*bhi(a2b.x) + Cca.y, 0.f);
        float p2 = fmaxf(K1a.z*blo(a1b.y) + K2a.z*blo(a2b.y) + Cca.z, 0.f);
        float p3 = fmaxf(K1a.w*bhi(a1b.y) + K2a.w*bhi(a2b.y) + Cca.w, 0.f);
        float p4 = fmaxf(K1b.x*blo(a1b.z) + K2b.x*blo(a2b.z) + Ccb.x, 0.f);
        float p5 = fmaxf(K1b.y*bhi(a1b.z) + K2b.y*bhi(a2b.z) + Ccb.y, 0.f);
        float p6 = fmaxf(K1b.z*blo(a1b.w) + K2b.z*blo(a2b.w) + Ccb.z, 0.f);
        float p7 = fmaxf(K1b.w*bhi(a1b.w) + K2b.w*bhi(a2b.w) + Ccb.w, 0.f);
        x1 = {pk2(p0, p1), pk2(p2, p3), pk2(p4, p5), pk2(p6, p7)};
      } else {
        // sym: pooled A = max(0, max_n(k1*a1_n + (k2*a2 + cc)))
        uint4 a2a = *reinterpret_cast<const uint4*>(&agg2[a2base + k0]);
        uint4 a2b = *reinterpret_cast<const uint4*>(&agg2[a2base + 64 * (size_t)NCOUT + k0]);
        float t0 = K2a.x*blo(a2a.x) + Cca.x, t1 = K2a.y*bhi(a2a.x) + Cca.y;
        float t2 = K2a.z*blo(a2a.y) + Cca.z, t3 = K2a.w*bhi(a2a.y) + Cca.w;
        float t4 = K2b.x*blo(a2a.z) + Ccb.x, t5 = K2b.y*bhi(a2a.z) + Ccb.y;
        float t6 = K2b.z*blo(a2a.w) + Ccb.z, t7 = K2b.w*bhi(a2a.w) + Ccb.w;
        float u0 = K2a.x*blo(a2b.x) + Cca.x, u1 = K2a.y*bhi(a2b.x) + Cca.y;
        float u2 = K2a.z*blo(a2b.y) + Cca.z, u3 = K2a.w*bhi(a2b.y) + Cca.w;
        float u4 = K2b.x*blo(a2b.z) + Ccb.x, u5 = K2b.y*bhi(a2b.z) + Ccb.y;
        float u6 = K2b.z*blo(a2b.w) + Ccb.z, u7 = K2b.w*bhi(a2b.w) + Ccb.w;
        float m0 = 0.f, m1 = 0.f, m2 = 0.f, m3 = 0.f, m4 = 0.f, m5 = 0.f, m6 = 0.f, m7 = 0.f;
        float e0 = 0.f, e1 = 0.f, e2 = 0.f, e3 = 0.f, e4 = 0.f, e5 = 0.f, e6 = 0.f, e7 = 0.f;
#pragma unroll
        for (int n = 0; n < 8; ++n) {
          uint4 a1a = *reinterpret_cast<const uint4*>(&AGG1[a1base + n * nstep + k0]);
          uint4 a1b = *reinterpret_cast<const uint4*>(&AGG1[a1base + n * nstep + 64 * (size_t)NCOUT + k0]);
          m0 = fmaxf(m0, K1a.x*blo(a1a.x) + t0); m1 = fmaxf(m1, K1a.y*bhi(a1a.x) + t1);
          m2 = fmaxf(m2, K1a.z*blo(a1a.y) + t2); m3 = fmaxf(m3, K1a.w*bhi(a1a.y) + t3);
          m4 = fmaxf(m4, K1b.x*blo(a1a.z) + t4); m5 = fmaxf(m5, K1b.y*bhi(a1a.z) + t5);
          m6 = fmaxf(m6, K1b.z*blo(a1a.w) + t6); m7 = fmaxf(m7, K1b.w*bhi(a1a.w) + t7);
          e0 = fmaxf(e0, K1a.x*blo(a1b.x) + u0); e1 = fmaxf(e1, K1a.y*bhi(a1b.x) + u1);
          e2 = fmaxf(e2, K1a.z*blo(a1b.y) + u2); e3 = fmaxf(e3, K1a.w*bhi(a1b.y) + u3);
          e4 = fmaxf(e4, K1b.x*blo(a1b.z) + u4); e5 = fmaxf(e5, K1b.y*bhi(a1b.z) + u5);
          e6 = fmaxf(e6, K1b.z*blo(a1b.w) + u6); e7 = fmaxf(e7, K1b.w*bhi(a1b.w) + u7);
        }
        x0 = {pk2(m0, m1), pk2(m2, m3), pk2(m4, m5), pk2(m6, m7)};
        x1 = {pk2(e0, e1), pk2(e2, e3), pk2(e4, e5), pk2(e6, e7)};
      }
    }
    __syncthreads();
    *reinterpret_cast<uint4*>(&Wsh[r0 * 40 + seg]) = w0;
    *reinterpret_cast<uint4*>(&Wsh[(r0 + 64) * 40 + seg]) = w1;
    *reinterpret_cast<uint4*>(&Xsh[r0 * 40 + seg]) = x0;
    *reinterpret_cast<uint4*>(&Xsh[(r0 + 64) * 40 + seg]) = x1;
    __syncthreads();
    bf16x8 af[4], bx[4];
#pragma unroll
    for (int fi = 0; fi < 4; ++fi)
      af[fi] = *reinterpret_cast<const bf16x8*>(&Wsh[(wm * 64 + fi * 16 + l) * 40 + q * 8]);
#pragma unroll
    for (int fj = 0; fj < 4; ++fj)
      bx[fj] = *reinterpret_cast<const bf16x8*>(&Xsh[(wn * 64 + fj * 16 + l) * 40 + q * 8]);
#pragma unroll
    for (int fi = 0; fi < 4; ++fi)
#pragma unroll
      for (int fj = 0; fj < 4; ++fj)
        acc[fi][fj] = __builtin_amdgcn_mfma_f32_16x16x32_bf16(af[fi], bx[fj], acc[fi][fj], 0, 0, 0);
  }
  __syncthreads();
  u16* Csh = smem;  // [128][136]
#pragma unroll
  for (int fi = 0; fi < 4; ++fi) {
#pragma unroll
    for (int fj = 0; fj < 4; ++fj) {
      int co_l = wm * 64 + fi * 16 + q * 4;
      int nd_l = wn * 64 + fj * 16 + l;
      uint2 pkd = {pk2(acc[fi][fj][0], acc[fi][fj][1]),
                   pk2(acc[fi][fj][2], acc[fi][fj][3])};
      *reinterpret_cast<uint2*>(&Csh[nd_l * 136 + co_l]) = pkd;
    }
  }
  __syncthreads();
#pragma unroll
  for (int p = 0; p < 8; ++p) {
    int idx = p * 256 + t;
    int nd = idx >> 4;
    int c8 = (idx & 15) * 8;
    uint4 v = *reinterpret_cast<const uint4*>(&Csh[nd * 136 + c8]);
    nt_store4(&out[((size_t)g * LNODES + n0 + nd) * NCOUT + c0 + c8], v.x, v.y, v.z, v.w);
  }
}

// ---------------- combined aggregation ----------------
// Big path (1024 blocks): half-wave g-split, lane = 8 channels (uint4).
// Edge loop: x4 unroll + exact tail (x8 in R12 doubled VGPR -> occupancy 25%,
// net regression; x4 keeps VGPR ~50 and ~40% occupancy).
// NT stores (kept from R12): proven FETCH 58->25 MB win.
__global__ __launch_bounds__(256) void agg_comb_k(const u16* __restrict__ HW1,
                                                  const u16* __restrict__ hw2,
                                                  const int* __restrict__ col,
                                                  const float* __restrict__ wn,
                                                  const int* __restrict__ rp,
                                                  const float* __restrict__ selfn,
                                                  u16* __restrict__ AGG1,
                                                  u16* __restrict__ agg2,
                                                  float* __restrict__ st) {
  __shared__ float lsum[8][NCOUT], lsq[8][NCOUT];
  const int bid = blockIdx.x;
  const int t = threadIdx.x;
  const int wv = t >> 6;
  float* sumO;
  float* sqO;
  int shard;
  if (bid < 1024) {
    int slot = bid >> 3;
    int chunk = slot & 63;
    int g0 = (bid & 7) + 8 * (slot >> 6);
    const int d0 = chunk * ND;
    const int h = (t >> 5) & 1;   // half-wave: which graph copy
    const int ch = (t & 31) * 8;  // channel octet
    const u16* baseh = HW1 + (size_t)(g0 + 16 * h) * LNODES * NCOUT;
    u16* outh = AGG1 + (size_t)(g0 + 16 * h) * LNODES * NCOUT;
    float s0 = 0.f, s1 = 0.f, s2 = 0.f, s3 = 0.f, s4 = 0.f, s5 = 0.f, s6 = 0.f, s7 = 0.f;
    float q0 = 0.f, q1 = 0.f, q2 = 0.f, q3 = 0.f, q4 = 0.f, q5 = 0.f, q6 = 0.f, q7 = 0.f;
    for (int i = wv; i < ND; i += 4) {
      int d = d0 + i;
      int e0 = rp[d], e1 = rp[d + 1];
      float sw = selfn[d];
      uint4 u = *reinterpret_cast<const uint4*>(&baseh[(size_t)d * NCOUT + ch]);
      float a0 = sw * blo(u.x), a1 = sw * bhi(u.x), a2 = sw * blo(u.y), a3 = sw * bhi(u.y);
      float a4 = sw * blo(u.z), a5 = sw * bhi(u.z), a6 = sw * blo(u.w), a7 = sw * bhi(u.w);
      int e = e0;
      const int e4 = e0 + ((e1 - e0) & ~3);
      for (; e < e4; e += 4) {
        int i0 = col[e + 0], i1 = col[e + 1], i2 = col[e + 2], i3 = col[e + 3];
        float w0 = wn[e + 0], w1 = wn[e + 1], w2 = wn[e + 2], w3 = wn[e + 3];
        uint4 v0 = *reinterpret_cast<const uint4*>(&baseh[(size_t)i0 * NCOUT + ch]);
        uint4 v1 = *reinterpret_cast<const uint4*>(&baseh[(size_t)i1 * NCOUT + ch]);
        uint4 v2 = *reinterpret_cast<const uint4*>(&baseh[(size_t)i2 * NCOUT + ch]);
        uint4 v3 = *reinterpret_cast<const uint4*>(&baseh[(size_t)i3 * NCOUT + ch]);
        a0 += w0 * blo(v0.x); a1 += w0 * bhi(v0.x); a2 += w0 * blo(v0.y); a3 += w0 * bhi(v0.y);
        a4 += w0 * blo(v0.z); a5 += w0 * bhi(v0.z); a6 += w0 * blo(v0.w); a7 += w0 * bhi(v0.w);
        a0 += w1 * blo(v1.x); a1 += w1 * bhi(v1.x); a2 += w1 * blo(v1.y); a3 += w1 * bhi(v1.y);
        a4 += w1 * blo(v1.z); a5 += w1 * bhi(v1.z); a6 += w1 * blo(v1.w); a7 += w1 * bhi(v1.w);
        a0 += w2 * blo(v2.x); a1 += w2 * bhi(v2.x); a2 += w2 * blo(v2.y); a3 += w2 * bhi(v2.y);
        a4 += w2 * blo(v2.z); a5 += w2 * bhi(v2.z); a6 += w2 * blo(v2.w); a7 += w2 * bhi(v2.w);
        a0 += w3 * blo(v3.x); a1 += w3 * bhi(v3.x); a2 += w3 * blo(v3.y); a3 += w3 * bhi(v3.y);
        a4 += w3 * blo(v3.z); a5 += w3 * bhi(v3.z); a6 += w3 * blo(v3.w); a7 += w3 * bhi(v3.w);
      }
      for (; e < e1; ++e) {
        int ci = col[e];
        float w = wn[e];
        uint4 v = *reinterpret_cast<const uint4*>(&baseh[(size_t)ci * NCOUT + ch]);
        a0 += w * blo(v.x); a1 += w * bhi(v.x); a2 += w * blo(v.y); a3 += w * bhi(v.y);
        a4 += w * blo(v.z); a5 += w * bhi(v.z); a6 += w * blo(v.w); a7 += w * bhi(v.w);
      }
      nt_store4(&outh[(size_t)d * NCOUT + ch],
                pk2(a0, a1), pk2(a2, a3), pk2(a4, a5), pk2(a6, a7));
      s0 += a0; s1 += a1; s2 += a2; s3 += a3; s4 += a4; s5 += a5; s6 += a6; s7 += a7;
      q0 += a0 * a0; q1 += a1 * a1; q2 += a2 * a2; q3 += a3 * a3;
      q4 += a4 * a4; q5 += a5 * a5; q6 += a6 * a6; q7 += a7 * a7;
    }
    int row = wv * 2 + h;
    float4 sa = {s0, s1, s2, s3}, sb = {s4, s5, s6, s7};
    float4 qa = {q0, q1, q2, q3}, qb = {q4, q5, q6, q7};
    *reinterpret_cast<float4*>(&lsum[row][ch]) = sa;
    *reinterpret_cast<float4*>(&lsum[row][ch + 4]) = sb;
    *reinterpret_cast<float4*>(&lsq[row][ch]) = qa;
    *reinterpret_cast<float4*>(&lsq[row][ch + 4]) = qb;
    sumO = st; sqO = st + 2048; shard = (bid & 7) * NCOUT;
  } else {
    int b2 = bid - 1024;
    int g = b2 & (GSM - 1);
    int chunk = b2 >> 2;
    const int d0 = chunk * ND;
    const int lc = (t & 63) * 4;
    const u16* base = hw2 + (size_t)g * LNODES * NCOUT;
    float4 s = {0.f, 0.f, 0.f, 0.f}, qq = {0.f, 0.f, 0.f, 0.f};
    for (int i = wv; i < ND; i += 4) {
      int d = d0 + i;
      int e0 = rp[d], e1 = rp[d + 1];
      float sw = selfn[d];
      uint2 u = *reinterpret_cast<const uint2*>(&base[(size_t)d * NCOUT + lc]);
      float4 a = {sw * blo(u.x), sw * bhi(u.x), sw * blo(u.y), sw * bhi(u.y)};
      int e = e0;
      const int e4 = e0 + ((e1 - e0) & ~3);
      for (; e < e4; e += 4) {
        int i0 = col[e + 0], i1 = col[e + 1], i2 = col[e + 2], i3 = col[e + 3];
        float w0 = wn[e + 0], w1 = wn[e + 1], w2 = wn[e + 2], w3 = wn[e + 3];
        uint2 v0 = *reinterpret_cast<const uint2*>(&base[(size_t)i0 * NCOUT + lc]);
        uint2 v1 = *reinterpret_cast<const uint2*>(&base[(size_t)i1 * NCOUT + lc]);
        uint2 v2 = *reinterpret_cast<const uint2*>(&base[(size_t)i2 * NCOUT + lc]);
        uint2 v3 = *reinterpret_cast<const uint2*>(&base[(size_t)i3 * NCOUT + lc]);
        a.x += w0 * blo(v0.x); a.y += w0 * bhi(v0.x); a.z += w0 * blo(v0.y); a.w += w0 * bhi(v0.y);
        a.x += w1 * blo(v1.x); a.y += w1 * bhi(v1.x); a.z += w1 * blo(v1.y); a.w += w1 * bhi(v1.y);
        a.x += w2 * blo(v2.x); a.y += w2 * bhi(v2.x); a.z += w2 * blo(v2.y); a.w += w2 * bhi(v2.y);
        a.x += w3 * blo(v3.x); a.y += w3 * bhi(v3.x); a.z += w3 * blo(v3.y); a.w += w3 * bhi(v3.y);
      }
      for (; e < e1; ++e) {
        float w = wn[e];
        uint2 v = *reinterpret_cast<const uint2*>(&base[(size_t)col[e] * NCOUT + lc]);
        a.x += w * blo(v.x); a.y += w * bhi(v.x); a.z += w * blo(v.y); a.w += w * bhi(v.y);
      }
      nt_store2(&agg2[((size_t)g * LNODES + d) * NCOUT + lc], pk2(a.x, a.y), pk2(a.z, a.w));
      s.x += a.x; s.y += a.y; s.z += a.z; s.w += a.w;
      qq.x += a.x * a.x; qq.y += a.y * a.y; qq.z += a.z * a.z; qq.w += a.w * a.w;
    }
    *reinterpret_cast<float4*>(&lsum[wv][lc]) = s;
    *reinterpret_cast<float4*>(&lsq[wv][lc]) = qq;
    float4 z4 = {0.f, 0.f, 0.f, 0.f};
    *reinterpret_cast<float4*>(&lsum[wv + 4][lc]) = z4;
    *reinterpret_cast<float4*>(&lsq[wv + 4][lc]) = z4;
    sumO = st + 4096; sqO = st + 6144; shard = (b2 & 7) * NCOUT;
  }
  __syncthreads();
  float ts = 0.f, tq = 0.f;
#pragma unroll
  for (int r = 0; r < 8; ++r) {
    ts += lsum[r][t];
    tq += lsq[r][t];
  }
  atomicAdd(&sumO[shard + t], ts);
  atomicAdd(&sqO[shard + t], tq);
}

// ---------------- layer 2: fuse + transpose to channel-major fp32 d_out ----------------
__global__ __launch_bounds__(256) void fuse_tr_bf_k(const u16* __restrict__ A1,
                                                    const u16* __restrict__ A2,
                                                    const float* __restrict__ st,
                                                    const float* __restrict__ ga,
                                                    const float* __restrict__ be,
                                                    const float* __restrict__ gs,
                                                    const float* __restrict__ bes,
                                                    float* __restrict__ O) {
  __shared__ float T[64][65];  // [node_local][co_local]
  __shared__ float lk1[NCOUT], lk2[NCOUT], lcc[NCOUT];
  const int g = blockIdx.z;
  const int d0 = blockIdx.x * 64;
  const int c0 = blockIdx.y * 64;
  const int b = g >> 3;
  const int t = threadIdx.x;
  coef_ld(st, ga, be, gs, bes, lk1, lk2, lcc, t);
  __syncthreads();
  const int tr = t >> 4;
  const int tc = (t & 15) * 4;
#pragma unroll
  for (int p = 0; p < 4; ++p) {
    int d = d0 + tr + p * 16;
    uint2 a1 = *reinterpret_cast<const uint2*>(&A1[((size_t)g * LNODES + d) * NCOUT + c0 + tc]);
    uint2 a2 = *reinterpret_cast<const uint2*>(&A2[((size_t)b * LNODES + d) * NCOUT + c0 + tc]);
    int cb = c0 + tc;
    T[tr + p * 16][tc + 0] = fmaxf(lk1[cb+0] * blo(a1.x) + lk2[cb+0] * blo(a2.x) + lcc[cb+0], 0.f);
    T[tr + p * 16][tc + 1] = fmaxf(lk1[cb+1] * bhi(a1.x) + lk2[cb+1] * bhi(a2.x) + lcc[cb+1], 0.f);
    T[tr + p * 16][tc + 2] = fmaxf(lk1[cb+2] * blo(a1.y) + lk2[cb+2] * blo(a2.y) + lcc[cb+2], 0.f);
    T[tr + p * 16][tc + 3] = fmaxf(lk1[cb+3] * bhi(a1.y) + lk2[cb+3] * bhi(a2.y) + lcc[cb+3], 0.f);
  }
  __syncthreads();
#pragma unroll
  for (int p = 0; p < 4; ++p) {
    int c = tr + p * 16;
    nt_storef4(&O[((size_t)g * NCOUT + c0 + c) * LNODES + d0 + tc],
               T[tc + 0][c], T[tc + 1][c], T[tc + 2][c], T[tc + 3][c]);
  }
}

// ---------------- launch ----------------

extern "C" void kernel_launch(void* const* d_in, const int* in_sizes, int n_in,
                              void* d_out, int out_size, void* d_ws, size_t ws_size,
                              hipStream_t stream) {
  const float* x_in = (const float*)d_in[0];
  const int* ei = (const int*)d_in[1];
  const float* W[3]   = {(const float*)d_in[2],  (const float*)d_in[4],  (const float*)d_in[6]};
  const float* Wsym[3]= {(const float*)d_in[8],  (const float*)d_in[10], (const float*)d_in[12]};
  const float* ga[3]  = {(const float*)d_in[14], (const float*)d_in[16], (const float*)d_in[18]};
  const float* be[3]  = {(const float*)d_in[15], (const float*)d_in[17], (const float*)d_in[19]};
  const float* gs[3]  = {(const float*)d_in[20], (const float*)d_in[22], (const float*)d_in[24]};
  const float* bes[3] = {(const float*)d_in[21], (const float*)d_in[23], (const float*)d_in[25]};

  const size_t EBIG = (size_t)GBIG * LNODES * NCOUT;  // 16.7M elems
  const size_t ESM = (size_t)GSM * LNODES * NCOUT;
  char* p = (char*)d_ws;
  u16* XT0  = (u16*)p; p += (size_t)GBIG * LNODES * 128 * 2;  // 16 MiB layer-0 input
  u16* AGG1 = (u16*)p; p += EBIG * 2;   // 32 MiB
  u16* agg2 = (u16*)p; p += ESM * 2;    // 4 MiB
  u16* xp   = (u16*)p; p += (size_t)GSM * LNODES * 128 * 2;   // 2 MiB (layer-0 only)
  u16* hw2  = (u16*)p; p += ESM * 2;    // 4 MiB
  u16* WbT[3], *WsT[3];
  for (int i = 0; i < 3; ++i) { WbT[i] = (u16*)p; p += NCOUT * NCOUT * 2; }
  for (int i = 0; i < 3; ++i) { WsT[i] = (u16*)p; p += NCOUT * NCOUT * 2; }
  int*   rp   = (int*)p;   p += 2064 * 4;
  float* dis  = (float*)p; p += LNODES * 4;
  float* selfn= (float*)p; p += LNODES * 4;
  char* zbase = p;
  float* deg  = (float*)p; p += LNODES * 4;
  int*   cnt  = (int*)p;   p += LNODES * 4;
  int*   fillc= (int*)p;   p += LNODES * 4;
  int*   col  = (int*)p;   p += (NEDGE + 8) * 4;  // padded, zeroed
  float* wn   = (float*)p; p += (NEDGE + 8) * 4;  // padded, zeroed
  float* stats= (float*)p; p += 3 * 4 * 2048 * 4; // [3 layers][sum1|sq1|sum2|sq2][8][256]
  size_t zsize = (size_t)(p - zbase);

  u16* HW1 = (u16*)d_out;  // big GEMM out in d_out (dead by fuse_tr time)
  float* stL[3] = {stats, stats + 8192, stats + 16384};

  // ---- setup: CSR + weights + input transpose + layer-0 pool ----
  hipMemsetAsync(zbase, 0, zsize, stream);
  count_deg_k<<<NEDGE / 256, 256, 0, stream>>>(ei, deg, cnt);
  dis_k<<<LNODES / 256, 256, 0, stream>>>(deg, dis, selfn);
  scan_k<<<1, 256, 0, stream>>>(cnt, rp);
  fill_k<<<NEDGE / 256, 256, 0, stream>>>(ei, rp, fillc, dis, col, wn);
  WCvt wc;
  for (int i = 0; i < 3; ++i) {
    wc.src[i] = W[i];     wc.dst[i] = WbT[i];     wc.ci[i] = (i == 0) ? 128 : 256;
    wc.src[3 + i] = Wsym[i]; wc.dst[3 + i] = WsT[i]; wc.ci[3 + i] = (i == 0) ? 128 : 256;
  }
  cvtw_all_k<<<dim3(4, 4, 6), 256, 0, stream>>>(wc);
  trans_k<<<dim3(LNODES / 64, 128 / 64, GBIG), 256, 0, stream>>>(x_in, XT0, 128);
  pool_bf_k<<<GSM * 128 * LNODES / 8 / 256, 256, 0, stream>>>(XT0, xp, 128 * LNODES);

  dim3 ggrid(LNODES / 128, NCOUT / 128, GBIG + GSM);
  for (int l = 0; l < 3; ++l) {
    if (l == 0) {
      gemm_all_k<0><<<ggrid, 256, 0, stream>>>(XT0, xp, AGG1, agg2, nullptr,
                                               nullptr, nullptr, nullptr, nullptr,
                                               WbT[l], WsT[l], HW1, hw2, 128);
    } else {
      gemm_all_k<1><<<ggrid, 256, 0, stream>>>(XT0, xp, AGG1, agg2, stL[l - 1],
                                               ga[l - 1], be[l - 1], gs[l - 1], bes[l - 1],
                                               WbT[l], WsT[l], HW1, hw2, NCOUT);
    }
    agg_comb_k<<<1280, 256, 0, stream>>>(HW1, hw2, col, wn, rp, selfn,
                                         AGG1, agg2, stL[l]);
  }
  fuse_tr_bf_k<<<dim3(LNODES / 64, NCOUT / 64, GBIG), 256, 0, stream>>>(
      AGG1, agg2, stL[2], ga[2], be[2], gs[2], bes[2], (float*)d_out);
}